// Round 14
// baseline (285.298 us; speedup 1.0000x reference)
//
#include <hip/hip_runtime.h>

#define NFEAT 256
#define NHID  128

#define NBK   391     // node buckets of 256 nodes (ceil(100000/256))
#define EPB   4096    // edges per block in the coarse pass
#define NBLK  391     // edge blocks (ceil(1600000/4096))
#define SEGW  4608    // fixed bucket segment stride (mean 4092 + 8 sigma)

typedef __bf16 bf16x8 __attribute__((ext_vector_type(8)));
typedef __bf16 bf16x4 __attribute__((ext_vector_type(4)));
typedef float  f32x4  __attribute__((ext_vector_type(4)));

// ---------------------------------------------------------------------------
// 1) Spectral norm (one power iteration) -> scal[0] = 1/sigma.
//    Also zeroes the global bucket_fill counters (free ride, 1 block).
// ---------------------------------------------------------------------------
__global__ __launch_bounds__(256) void sigma_kernel(const float* __restrict__ W,
                                                    const float* __restrict__ u,
                                                    float* __restrict__ scal,
                                                    int* __restrict__ bucket_fill) {
    __shared__ float v[NHID];
    __shared__ float red[256];
    int tid = threadIdx.x;

    if (tid < NBK) bucket_fill[tid] = 0;
    if (tid + 256 < NBK) bucket_fill[tid + 256] = 0;

    float t = 0.f;
    if (tid < NHID) {
        for (int i = 0; i < NFEAT; ++i) t += W[i * NHID + tid] * u[i];
    }
    red[tid] = (tid < NHID) ? t * t : 0.f;
    __syncthreads();
    for (int s = 128; s > 0; s >>= 1) {
        if (tid < s) red[tid] += red[tid + s];
        __syncthreads();
    }
    float nv = sqrtf(red[0]);
    float inv_nv = 1.f / (nv + 1e-12f);
    __syncthreads();
    if (tid < NHID) v[tid] = t * inv_nv;
    __syncthreads();

    float wv = 0.f;
    for (int j = 0; j < NHID; ++j) wv += W[tid * NHID + j] * v[j];
    red[tid] = wv * wv;
    __syncthreads();
    for (int s = 128; s > 0; s >>= 1) {
        if (tid < s) red[tid] += red[tid + s];
        __syncthreads();
    }
    if (tid == 0) {
        float n2  = red[0];
        float nwv = sqrtf(n2);
        float sigma = n2 / (nwv + 1e-12f);
        scal[0] = 1.f / sigma;
    }
}

// ---------------------------------------------------------------------------
// 2) W^T in bf16, scaled by 1/sigma
// ---------------------------------------------------------------------------
__global__ __launch_bounds__(256) void wt_kernel(const float* __restrict__ W,
                                                 const float* __restrict__ scal,
                                                 __bf16* __restrict__ WT) {
    int idx = blockIdx.x * 256 + threadIdx.x;
    int c = idx >> 8;
    int r = idx & 255;
    WT[c * NFEAT + r] = (__bf16)(W[r * NHID + c] * scal[0]);
}

// ---------------------------------------------------------------------------
// 3) FUSED kernel: blocks [0, ngemm) = MFMA GEMM (B double-buffered);
//    blocks [ngemm, ngemm+NBLK) = coarse edge bucketing. Union LDS 32KB.
// ---------------------------------------------------------------------------
__global__ __launch_bounds__(256) void fused_kernel(const float* __restrict__ x,
                                                    const __bf16* __restrict__ WT,
                                                    __bf16* __restrict__ xwb,
                                                    const int* __restrict__ erow,
                                                    const int* __restrict__ ecol,
                                                    int* __restrict__ bucket_fill,
                                                    unsigned int* __restrict__ rbuf,
                                                    int nn, int E, int ngemm) {
    __shared__ __attribute__((aligned(16))) char sbuf[32768];

    int tid  = threadIdx.x;

    if ((int)blockIdx.x < ngemm) {
        // =================== GEMM path (B prefetch distance 1) ==============
        float (*xs)[64][64] = (float (*)[64][64])sbuf;   // 2 x 16KB fp32 tiles

        int lane = tid & 63;
        int w    = tid >> 6;                 // wave 0..3
        int rfrag = lane & 15;
        int kg    = lane >> 4;               // 0..3
        int row0 = blockIdx.x * 64;

        int p16  = lane & 15;                // staging: 16B slot within row
        int rsub = lane >> 4;                // staging: row within 4-row group

        int crow0 = (w & 1) * 32 + rfrag;
        int col0  = (w >> 1) * 64;
        int r0 = row0 + crow0;
        int r1 = r0 + 16;
        const __bf16* wb = WT + (size_t)(col0 + rfrag) * NFEAT + kg * 8;
        int cr7 = crow0 & 7;

        f32x4 acc0[4] = {};
        f32x4 acc1[4] = {};

        auto STAGE = [&](int buf, int c) {
#pragma unroll
            for (int j = 0; j < 4; ++j) {
                int rloc = w * 16 + j * 4 + rsub;
                int grow = row0 + rloc;
                if (grow >= nn) grow = nn - 1;
                const float* src = x + (size_t)grow * NFEAT + c * 64 + ((p16 ^ (grow & 7)) << 2);
                __builtin_amdgcn_global_load_lds(
                    (const __attribute__((address_space(1))) void*)src,
                    (__attribute__((address_space(3))) void*)&xs[buf][w * 16 + j * 4][0],
                    16, 0, 0);
            }
        };

        bf16x8 Bf[2][2][4];                  // [buf][ks][nt] -- double-buffered
        auto BLOAD = [&](int bbuf, int c) {
#pragma unroll
            for (int ks = 0; ks < 2; ++ks)
#pragma unroll
                for (int nt = 0; nt < 4; ++nt)
                    Bf[bbuf][ks][nt] = *(const bf16x8*)(wb + (size_t)nt * 16 * NFEAT + c * 64 + ks * 32);
        };

        auto MFMA_CHUNK = [&](int buf, int bbuf) {
#pragma unroll
            for (int ks = 0; ks < 2; ++ks) {
                int sA = kg * 2 + ks * 8;
                float4 a0lo = *(const float4*)&xs[buf][crow0][((sA) ^ cr7) * 4];
                float4 a0hi = *(const float4*)&xs[buf][crow0][((sA + 1) ^ cr7) * 4];
                float4 a1lo = *(const float4*)&xs[buf][crow0 + 16][((sA) ^ cr7) * 4];
                float4 a1hi = *(const float4*)&xs[buf][crow0 + 16][((sA + 1) ^ cr7) * 4];
                bf16x8 af0, af1;
                af0[0] = (__bf16)a0lo.x; af0[1] = (__bf16)a0lo.y;
                af0[2] = (__bf16)a0lo.z; af0[3] = (__bf16)a0lo.w;
                af0[4] = (__bf16)a0hi.x; af0[5] = (__bf16)a0hi.y;
                af0[6] = (__bf16)a0hi.z; af0[7] = (__bf16)a0hi.w;
                af1[0] = (__bf16)a1lo.x; af1[1] = (__bf16)a1lo.y;
                af1[2] = (__bf16)a1lo.z; af1[3] = (__bf16)a1lo.w;
                af1[4] = (__bf16)a1hi.x; af1[5] = (__bf16)a1hi.y;
                af1[6] = (__bf16)a1hi.z; af1[7] = (__bf16)a1hi.w;
#pragma unroll
                for (int nt = 0; nt < 4; ++nt) {
                    acc0[nt] = __builtin_amdgcn_mfma_f32_16x16x32_bf16(Bf[bbuf][ks][nt], af0, acc0[nt], 0, 0, 0);
                    acc1[nt] = __builtin_amdgcn_mfma_f32_16x16x32_bf16(Bf[bbuf][ks][nt], af1, acc1[nt], 0, 0, 0);
                }
            }
        };

#define DRAIN_BAR() do { \
            asm volatile("s_waitcnt vmcnt(0)" ::: "memory"); \
            __builtin_amdgcn_s_barrier(); } while (0)

        STAGE(0, 0);
        BLOAD(0, 0);
        DRAIN_BAR();

        BLOAD(1, 1);
        STAGE(1, 1);
        __builtin_amdgcn_sched_barrier(0);
        MFMA_CHUNK(0, 0);
        DRAIN_BAR();

        BLOAD(0, 2);
        STAGE(0, 2);
        __builtin_amdgcn_sched_barrier(0);
        MFMA_CHUNK(1, 1);
        DRAIN_BAR();

        BLOAD(1, 3);
        STAGE(1, 3);
        __builtin_amdgcn_sched_barrier(0);
        MFMA_CHUNK(0, 0);
        DRAIN_BAR();

        MFMA_CHUNK(1, 1);
#undef DRAIN_BAR

        if (r0 < nn) {
            __bf16* orow = xwb + (size_t)r0 * NHID + col0 + kg * 4;
#pragma unroll
            for (int nt = 0; nt < 4; ++nt) {
                bf16x4 v;
                v[0] = (__bf16)acc0[nt][0];
                v[1] = (__bf16)acc0[nt][1];
                v[2] = (__bf16)acc0[nt][2];
                v[3] = (__bf16)acc0[nt][3];
                *(bf16x4*)&orow[nt * 16] = v;
            }
        }
        if (r1 < nn) {
            __bf16* orow = xwb + (size_t)r1 * NHID + col0 + kg * 4;
#pragma unroll
            for (int nt = 0; nt < 4; ++nt) {
                bf16x4 v;
                v[0] = (__bf16)acc1[nt][0];
                v[1] = (__bf16)acc1[nt][1];
                v[2] = (__bf16)acc1[nt][2];
                v[3] = (__bf16)acc1[nt][3];
                *(bf16x4*)&orow[nt * 16] = v;
            }
        }
        return;
    }

    // =================== COARSE path (fixed-stride segments) ===============
    unsigned int*   rec   = (unsigned int*)sbuf;               // 16384 B
    unsigned short* bkk   = (unsigned short*)(sbuf + 16384);   //  8192 B
    int*            hist  = (int*)(sbuf + 24576);              //  1564 B
    int*            lbase = (int*)(sbuf + 24576 + 1564);
    int*            lfill = (int*)(sbuf + 24576 + 3128);
    int*            gb    = (int*)(sbuf + 24576 + 4692);       // ends 30832

    int b = blockIdx.x - ngemm;
    for (int k = tid; k < NBK; k += 256) { hist[k] = 0; lfill[k] = 0; }
    __syncthreads();

    int e0 = b * EPB;
    unsigned int rv[16];
    int kv[16];
#pragma unroll
    for (int j = 0; j < 16; ++j) {
        int idx = e0 + j * 256 + tid;
        if (idx < E) {
            int c = ecol[idx];
            int s = erow[idx];
            int k = c >> 8;
            kv[j] = k;
            rv[j] = ((unsigned int)(c & 255) << 24) | (unsigned int)s;
            atomicAdd(&hist[k], 1);
        } else kv[j] = -1;
    }
    __syncthreads();

    // wave-0 shuffle scan of hist[0..390] -> lbase (exclusive)
    if (tid < 64) {
        int carry = 0;
        for (int c0 = 0; c0 < NBK; c0 += 64) {
            int i = c0 + tid;
            int vv = (i < NBK) ? hist[i] : 0;
            int orig = vv;
#pragma unroll
            for (int d = 1; d < 64; d <<= 1) {
                int t = __shfl_up(vv, (unsigned)d, 64);
                if (tid >= d) vv += t;
            }
            if (i < NBK) lbase[i] = carry + vv - orig;
            carry += __shfl(vv, 63, 64);
        }
    }
    __syncthreads();

    // reserve global span per bucket
    if (tid < NBK) gb[tid] = tid * SEGW + atomicAdd(&bucket_fill[tid], hist[tid]);
    if (tid + 256 < NBK) gb[tid + 256] = (tid + 256) * SEGW
                                       + atomicAdd(&bucket_fill[tid + 256], hist[tid + 256]);
    __syncthreads();

#pragma unroll
    for (int j = 0; j < 16; ++j) {
        if (kv[j] >= 0) {
            int p = lbase[kv[j]] + atomicAdd(&lfill[kv[j]], 1);
            rec[p] = rv[j];
            bkk[p] = (unsigned short)kv[j];
        }
    }
    __syncthreads();

    int nval = E - e0;
    if (nval > EPB) nval = EPB;
    for (int p = tid; p < nval; p += 256) {
        int k = bkk[p];
        rbuf[gb[k] + (p - lbase[k])] = rec[p];
    }
}

// ---------------------------------------------------------------------------
// 4) F: fine pass — one block per bucket. Writes per-node meta (base,cnt,dinv)
//    and the dinv array (for per-edge loads), then places sources into ebuf.
// ---------------------------------------------------------------------------
__global__ __launch_bounds__(256) void fine_kernel(const unsigned int* __restrict__ rbuf,
                                                   const int* __restrict__ bucket_fill,
                                                   int4* __restrict__ meta,
                                                   float* __restrict__ dinv,
                                                   int* __restrict__ ebuf, int n) {
    __shared__ int cnt[256], lb[256], lf[256], sc[256];
    int tid = threadIdx.x, k = blockIdx.x;
    int seg0 = k * SEGW, seg1 = seg0 + bucket_fill[k];
    cnt[tid] = 0;
    lf[tid] = 0;
    __syncthreads();
    for (int j = seg0 + tid; j < seg1; j += 256)
        atomicAdd(&cnt[rbuf[j] >> 24], 1);
    __syncthreads();
    int cv = cnt[tid];
    sc[tid] = cv;
    __syncthreads();
    int val = cv;
    for (int off = 1; off < 256; off <<= 1) {
        int t = (tid >= off) ? sc[tid - off] : 0;
        __syncthreads();
        val += t;
        sc[tid] = val;
        __syncthreads();
    }
    lb[tid] = val - cv;   // exclusive
    __syncthreads();
    int node = k * 256 + tid;
    if (node < n) {
        float dv = rsqrtf((float)cv + 1.f);
        int4 m;
        m.x = seg0 + lb[tid];
        m.y = cv;
        m.z = __float_as_int(dv);
        m.w = 0;
        meta[node] = m;
        dinv[node] = dv;
    }
    for (int j = seg0 + tid; j < seg1; j += 256) {
        unsigned int r = rbuf[j];
        int dl = r >> 24;
        int p = seg0 + lb[dl] + atomicAdd(&lf[dl], 1);
        ebuf[p] = (int)(r & 0xFFFFFFu);
    }
}

// ---------------------------------------------------------------------------
// 5) Gather + finalize, XCD-SLICED: block b handles feature-slice s = b&7
//    (32B of each xwb row) for a 32-node group. All slice-s blocks land on
//    XCD s (blockIdx%8 round-robin), so each XCD's xwb working set is the
//    3.2MB column strip -> L2-resident; edge-payload reads become L2 hits.
//    Group = 8 lanes x 1 dword (2 bf16) per row; unroll 4 = 4 chains/group.
// ---------------------------------------------------------------------------
__global__ __launch_bounds__(256) void gather_kernel(const unsigned int* __restrict__ xbd,
                                                     const int4* __restrict__ meta,
                                                     const int* __restrict__ ebuf,
                                                     const float* __restrict__ dinv,
                                                     const float* __restrict__ bias,
                                                     const float* __restrict__ pa,
                                                     float* __restrict__ out, int n) {
    int tid = threadIdx.x;
    int l = tid & 7;                                  // lane within 8-lane group
    int s = blockIdx.x & 7;                           // feature slice -> XCD
    int node = (blockIdx.x >> 3) * 32 + (tid >> 3);   // 32 nodes per block
    if (node >= n) return;

    int4 m = meta[node];
    int b = m.x, deg = m.y;
    float dn = __int_as_float(m.z);
    int co = s * 8 + l;                               // dword column
    const unsigned int* xc = xbd + co;

    unsigned int v = xc[(size_t)node * 64];
    float a0 = dn * __uint_as_float(v << 16);
    float a1 = dn * __uint_as_float(v & 0xffff0000u);

    int k = 0;
    for (; k + 4 <= deg; k += 4) {
        int r0 = ebuf[b + k + 0];
        int r1 = ebuf[b + k + 1];
        int r2 = ebuf[b + k + 2];
        int r3 = ebuf[b + k + 3];
        float d0 = dinv[r0], d1 = dinv[r1], d2 = dinv[r2], d3 = dinv[r3];
        unsigned int v0 = xc[(size_t)r0 * 64];
        unsigned int v1 = xc[(size_t)r1 * 64];
        unsigned int v2 = xc[(size_t)r2 * 64];
        unsigned int v3 = xc[(size_t)r3 * 64];
        a0 += d0 * __uint_as_float(v0 << 16) + d1 * __uint_as_float(v1 << 16)
            + d2 * __uint_as_float(v2 << 16) + d3 * __uint_as_float(v3 << 16);
        a1 += d0 * __uint_as_float(v0 & 0xffff0000u) + d1 * __uint_as_float(v1 & 0xffff0000u)
            + d2 * __uint_as_float(v2 & 0xffff0000u) + d3 * __uint_as_float(v3 & 0xffff0000u);
    }
    for (; k < deg; ++k) {
        int r = ebuf[b + k];
        float d = dinv[r];
        unsigned int vv = xc[(size_t)r * 64];
        a0 += d * __uint_as_float(vv << 16);
        a1 += d * __uint_as_float(vv & 0xffff0000u);
    }

    float alpha = pa[0];
    float2 bb = ((const float2*)bias)[co];
    float o0 = dn * a0 + bb.x;
    float o1 = dn * a1 + bb.y;
    o0 = o0 > 0.f ? o0 : alpha * o0;
    o1 = o1 > 0.f ? o1 : alpha * o1;
    ((float2*)out)[(size_t)node * 64 + co] = make_float2(o0, o1);
}

// ---------------------------------------------------------------------------
extern "C" void kernel_launch(void* const* d_in, const int* in_sizes, int n_in,
                              void* d_out, int out_size, void* d_ws, size_t ws_size,
                              hipStream_t stream) {
    const float* x    = (const float*)d_in[0];
    const int*   ei   = (const int*)d_in[1];   // int32, [2,E] row-major
    const float* W    = (const float*)d_in[2];
    const float* bias = (const float*)d_in[3];
    const float* pa   = (const float*)d_in[4];
    const float* u    = (const float*)d_in[5];

    int n = in_sizes[0] / NFEAT;     // 100000
    int e = in_sizes[1] / 2;         // 1600000
    const int* erow = ei;            // sources
    const int* ecol = ei + e;        // targets

    float* out = (float*)d_out;
    char* ws = (char*)d_ws;
    // workspace layout (bytes)
    float*        scal   = (float*)(ws);                    // 4 B
    int*          bfill  = (int*)  (ws + 0x0002000);        // 391 ints
    __bf16*       WT     = (__bf16*)(ws + 0x0010000);       // 64 KB
    float*        dinv   = (float*)(ws + 0x0100000);        // 400 KB
    int4*         meta   = (int4*) (ws + 0x0200000);        // 1.6 MB
    unsigned int* rbuf   = (unsigned int*)(ws + 0x0400000); // 7.2 MB (391*4608*4)
    int*          ebuf   = (int*)  (ws + 0x0B00000);        // 7.2 MB
    __bf16*       xwb    = (__bf16*)(ws + 0x1200000);       // 25.6 MB

    int ngemm = (n + 63) / 64;       // 1563

    sigma_kernel<<<1, 256, 0, stream>>>(W, u, scal, bfill);
    wt_kernel<<<(NFEAT * NHID) / 256, 256, 0, stream>>>(W, scal, WT);

    fused_kernel<<<ngemm + NBLK, 256, 0, stream>>>(x, WT, xwb, erow, ecol,
                                                   bfill, rbuf, n, e, ngemm);

    fine_kernel<<<NBK, 256, 0, stream>>>(rbuf, bfill, meta, dinv, ebuf, n);

    int ngroups = (n + 31) / 32;     // 3125
    gather_kernel<<<ngroups * 8, 256, 0, stream>>>(
        (const unsigned int*)xwb, meta, ebuf, dinv, bias, pa, out, n);
}

// Round 16
// 145.535 us; speedup vs baseline: 1.9603x; 1.9603x over previous
//
#include <hip/hip_runtime.h>

#define NFEAT 256
#define NHID  128

#define NBK   391     // node buckets of 256 nodes (ceil(100000/256))
#define EPB   4096    // edges per block in the coarse pass
#define NBLK  391     // edge blocks (ceil(1600000/4096))
#define SEGW  4608    // fixed bucket segment stride (mean 4092 + 8 sigma)

typedef __bf16 bf16x8 __attribute__((ext_vector_type(8)));
typedef __bf16 bf16x4 __attribute__((ext_vector_type(4)));
typedef float  f32x4  __attribute__((ext_vector_type(4)));

#define PIN() __builtin_amdgcn_sched_barrier(0)

// ---------------------------------------------------------------------------
// 1) Spectral norm (one power iteration) -> scal[0] = 1/sigma.
//    Also zeroes the global bucket_fill counters (free ride, 1 block).
// ---------------------------------------------------------------------------
__global__ __launch_bounds__(256) void sigma_kernel(const float* __restrict__ W,
                                                    const float* __restrict__ u,
                                                    float* __restrict__ scal,
                                                    int* __restrict__ bucket_fill) {
    __shared__ float v[NHID];
    __shared__ float red[256];
    int tid = threadIdx.x;

    if (tid < NBK) bucket_fill[tid] = 0;
    if (tid + 256 < NBK) bucket_fill[tid + 256] = 0;

    float t = 0.f;
    if (tid < NHID) {
        for (int i = 0; i < NFEAT; ++i) t += W[i * NHID + tid] * u[i];
    }
    red[tid] = (tid < NHID) ? t * t : 0.f;
    __syncthreads();
    for (int s = 128; s > 0; s >>= 1) {
        if (tid < s) red[tid] += red[tid + s];
        __syncthreads();
    }
    float nv = sqrtf(red[0]);
    float inv_nv = 1.f / (nv + 1e-12f);
    __syncthreads();
    if (tid < NHID) v[tid] = t * inv_nv;
    __syncthreads();

    float wv = 0.f;
    for (int j = 0; j < NHID; ++j) wv += W[tid * NHID + j] * v[j];
    red[tid] = wv * wv;
    __syncthreads();
    for (int s = 128; s > 0; s >>= 1) {
        if (tid < s) red[tid] += red[tid + s];
        __syncthreads();
    }
    if (tid == 0) {
        float n2  = red[0];
        float nwv = sqrtf(n2);
        float sigma = n2 / (nwv + 1e-12f);
        scal[0] = 1.f / sigma;
    }
}

// ---------------------------------------------------------------------------
// 2) W^T in bf16, scaled by 1/sigma
// ---------------------------------------------------------------------------
__global__ __launch_bounds__(256) void wt_kernel(const float* __restrict__ W,
                                                 const float* __restrict__ scal,
                                                 __bf16* __restrict__ WT) {
    int idx = blockIdx.x * 256 + threadIdx.x;
    int c = idx >> 8;
    int r = idx & 255;
    WT[c * NFEAT + r] = (__bf16)(W[r * NHID + c] * scal[0]);
}

// ---------------------------------------------------------------------------
// 3) FUSED kernel: blocks [0, ngemm) = MFMA GEMM with 3-buffer LDS pipeline
//    (stage distance 2, counted vmcnt, issue order PINNED by sched_barrier);
//    blocks [ngemm, ngemm+NBLK) = coarse edge bucketing. Union LDS 48KB.
//
//    Ledger (S=4 gload_lds, B=8 reg loads, order pinned):
//      P : S0|B0|S1  vmcnt(12)->S0  barrier
//      I0: B1|S2  MFMA(b0,B0)[auto] vmcnt(12)->S1  barrier
//      I1: B2|S3  MFMA(b1,B1)[auto] vmcnt(12)->S2  barrier
//      I2: B3     MFMA(b2,B2)[auto] vmcnt(8) ->S3  barrier
//      I3:        MFMA(b0,B3)[auto] ; epilogue
// ---------------------------------------------------------------------------
__global__ __launch_bounds__(256) void fused_kernel(const float* __restrict__ x,
                                                    const __bf16* __restrict__ WT,
                                                    __bf16* __restrict__ xwb,
                                                    const int* __restrict__ erow,
                                                    const int* __restrict__ ecol,
                                                    int* __restrict__ bucket_fill,
                                                    unsigned int* __restrict__ rbuf,
                                                    int nn, int E, int ngemm) {
    __shared__ __attribute__((aligned(16))) char sbuf[49152];   // 48KB union

    int tid  = threadIdx.x;

    if ((int)blockIdx.x < ngemm) {
        // =================== GEMM path (3-buf, distance-2 stage) ============
        float (*xs)[64][64] = (float (*)[64][64])sbuf;   // 3 x 16KB fp32 tiles

        int lane = tid & 63;
        int w    = tid >> 6;                 // wave 0..3
        int rfrag = lane & 15;
        int kg    = lane >> 4;               // 0..3
        int row0 = blockIdx.x * 64;

        int p16  = lane & 15;                // staging: 16B slot within row
        int rsub = lane >> 4;                // staging: row within 4-row group

        int crow0 = (w & 1) * 32 + rfrag;
        int col0  = (w >> 1) * 64;
        int r0 = row0 + crow0;
        int r1 = r0 + 16;
        const __bf16* wb = WT + (size_t)(col0 + rfrag) * NFEAT + kg * 8;
        int cr7 = crow0 & 7;

        f32x4 acc0[4] = {};
        f32x4 acc1[4] = {};

        auto STAGE = [&](int buf, int c) {
#pragma unroll
            for (int j = 0; j < 4; ++j) {
                int rloc = w * 16 + j * 4 + rsub;
                int grow = row0 + rloc;
                if (grow >= nn) grow = nn - 1;
                const float* src = x + (size_t)grow * NFEAT + c * 64 + ((p16 ^ (grow & 7)) << 2);
                __builtin_amdgcn_global_load_lds(
                    (const __attribute__((address_space(1))) void*)src,
                    (__attribute__((address_space(3))) void*)&xs[buf][w * 16 + j * 4][0],
                    16, 0, 0);
            }
        };

        bf16x8 Bf[2][2][4];                  // [bbuf][ks][nt] double-buffered
        auto BLOAD = [&](int bbuf, int c) {
#pragma unroll
            for (int ks = 0; ks < 2; ++ks)
#pragma unroll
                for (int nt = 0; nt < 4; ++nt)
                    Bf[bbuf][ks][nt] = *(const bf16x8*)(wb + (size_t)nt * 16 * NFEAT + c * 64 + ks * 32);
        };

        auto MFMA_CHUNK = [&](int buf, int bbuf) {
#pragma unroll
            for (int ks = 0; ks < 2; ++ks) {
                int sA = kg * 2 + ks * 8;
                float4 a0lo = *(const float4*)&xs[buf][crow0][((sA) ^ cr7) * 4];
                float4 a0hi = *(const float4*)&xs[buf][crow0][((sA + 1) ^ cr7) * 4];
                float4 a1lo = *(const float4*)&xs[buf][crow0 + 16][((sA) ^ cr7) * 4];
                float4 a1hi = *(const float4*)&xs[buf][crow0 + 16][((sA + 1) ^ cr7) * 4];
                bf16x8 af0, af1;
                af0[0] = (__bf16)a0lo.x; af0[1] = (__bf16)a0lo.y;
                af0[2] = (__bf16)a0lo.z; af0[3] = (__bf16)a0lo.w;
                af0[4] = (__bf16)a0hi.x; af0[5] = (__bf16)a0hi.y;
                af0[6] = (__bf16)a0hi.z; af0[7] = (__bf16)a0hi.w;
                af1[0] = (__bf16)a1lo.x; af1[1] = (__bf16)a1lo.y;
                af1[2] = (__bf16)a1lo.z; af1[3] = (__bf16)a1lo.w;
                af1[4] = (__bf16)a1hi.x; af1[5] = (__bf16)a1hi.y;
                af1[6] = (__bf16)a1hi.z; af1[7] = (__bf16)a1hi.w;
#pragma unroll
                for (int nt = 0; nt < 4; ++nt) {
                    acc0[nt] = __builtin_amdgcn_mfma_f32_16x16x32_bf16(Bf[bbuf][ks][nt], af0, acc0[nt], 0, 0, 0);
                    acc1[nt] = __builtin_amdgcn_mfma_f32_16x16x32_bf16(Bf[bbuf][ks][nt], af1, acc1[nt], 0, 0, 0);
                }
            }
        };

        // ---- prologue  (issue order pinned: S0 | B0 | S1)
        STAGE(0, 0);  PIN();                           // S0
        BLOAD(0, 0);  PIN();                           // B0
        STAGE(1, 1);  PIN();                           // S1
        asm volatile("s_waitcnt vmcnt(12)" ::: "memory");   // retires S0
        __builtin_amdgcn_s_barrier();

        // ---- I0  (B1 | S2 | compute b0)
        BLOAD(1, 1);  PIN();                           // B1
        STAGE(2, 2);  PIN();                           // S2
        MFMA_CHUNK(0, 0);                              // auto-wait retires B0
        asm volatile("s_waitcnt vmcnt(12)" ::: "memory");   // retires S1
        __builtin_amdgcn_s_barrier();

        // ---- I1  (B2 | S3 | compute b1)
        BLOAD(0, 2);  PIN();                           // B2
        STAGE(0, 3);  PIN();                           // S3 -> buf0 (free)
        MFMA_CHUNK(1, 1);                              // auto retires B1
        asm volatile("s_waitcnt vmcnt(12)" ::: "memory");   // retires S2
        __builtin_amdgcn_s_barrier();

        // ---- I2  (B3 | compute b2)
        BLOAD(1, 3);  PIN();                           // B3
        MFMA_CHUNK(2, 0);                              // auto retires B2
        asm volatile("s_waitcnt vmcnt(8)" ::: "memory");    // retires S3
        __builtin_amdgcn_s_barrier();

        // ---- I3  (compute b0 = chunk3)
        MFMA_CHUNK(0, 1);                              // auto retires B3

        if (r0 < nn) {
            __bf16* orow = xwb + (size_t)r0 * NHID + col0 + kg * 4;
#pragma unroll
            for (int nt = 0; nt < 4; ++nt) {
                bf16x4 v;
                v[0] = (__bf16)acc0[nt][0];
                v[1] = (__bf16)acc0[nt][1];
                v[2] = (__bf16)acc0[nt][2];
                v[3] = (__bf16)acc0[nt][3];
                *(bf16x4*)&orow[nt * 16] = v;
            }
        }
        if (r1 < nn) {
            __bf16* orow = xwb + (size_t)r1 * NHID + col0 + kg * 4;
#pragma unroll
            for (int nt = 0; nt < 4; ++nt) {
                bf16x4 v;
                v[0] = (__bf16)acc1[nt][0];
                v[1] = (__bf16)acc1[nt][1];
                v[2] = (__bf16)acc1[nt][2];
                v[3] = (__bf16)acc1[nt][3];
                *(bf16x4*)&orow[nt * 16] = v;
            }
        }
        return;
    }

    // =================== COARSE path (fixed-stride segments) ===============
    unsigned int*   rec   = (unsigned int*)sbuf;               // 16384 B
    unsigned short* bkk   = (unsigned short*)(sbuf + 16384);   //  8192 B
    int*            hist  = (int*)(sbuf + 24576);              //  1564 B
    int*            lbase = (int*)(sbuf + 24576 + 1564);
    int*            lfill = (int*)(sbuf + 24576 + 3128);
    int*            gb    = (int*)(sbuf + 24576 + 4692);       // ends 30832

    int b = blockIdx.x - ngemm;
    for (int k = tid; k < NBK; k += 256) { hist[k] = 0; lfill[k] = 0; }
    __syncthreads();

    int e0 = b * EPB;
    unsigned int rv[16];
    int kv[16];
#pragma unroll
    for (int j = 0; j < 16; ++j) {
        int idx = e0 + j * 256 + tid;
        if (idx < E) {
            int c = ecol[idx];
            int s = erow[idx];
            int k = c >> 8;
            kv[j] = k;
            rv[j] = ((unsigned int)(c & 255) << 24) | (unsigned int)s;
            atomicAdd(&hist[k], 1);
        } else kv[j] = -1;
    }
    __syncthreads();

    // wave-0 shuffle scan of hist[0..390] -> lbase (exclusive)
    if (tid < 64) {
        int carry = 0;
        for (int c0 = 0; c0 < NBK; c0 += 64) {
            int i = c0 + tid;
            int vv = (i < NBK) ? hist[i] : 0;
            int orig = vv;
#pragma unroll
            for (int d = 1; d < 64; d <<= 1) {
                int t = __shfl_up(vv, (unsigned)d, 64);
                if (tid >= d) vv += t;
            }
            if (i < NBK) lbase[i] = carry + vv - orig;
            carry += __shfl(vv, 63, 64);
        }
    }
    __syncthreads();

    // reserve global span per bucket
    if (tid < NBK) gb[tid] = tid * SEGW + atomicAdd(&bucket_fill[tid], hist[tid]);
    if (tid + 256 < NBK) gb[tid + 256] = (tid + 256) * SEGW
                                       + atomicAdd(&bucket_fill[tid + 256], hist[tid + 256]);
    __syncthreads();

#pragma unroll
    for (int j = 0; j < 16; ++j) {
        if (kv[j] >= 0) {
            int p = lbase[kv[j]] + atomicAdd(&lfill[kv[j]], 1);
            rec[p] = rv[j];
            bkk[p] = (unsigned short)kv[j];
        }
    }
    __syncthreads();

    int nval = E - e0;
    if (nval > EPB) nval = EPB;
    for (int p = tid; p < nval; p += 256) {
        int k = bkk[p];
        rbuf[gb[k] + (p - lbase[k])] = rec[p];
    }
}

// ---------------------------------------------------------------------------
// 4) F: fine pass — one block per bucket. Writes per-node meta (base,cnt,dinv)
//    and the dinv array (for per-edge loads), then places sources into ebuf.
// ---------------------------------------------------------------------------
__global__ __launch_bounds__(256) void fine_kernel(const unsigned int* __restrict__ rbuf,
                                                   const int* __restrict__ bucket_fill,
                                                   int4* __restrict__ meta,
                                                   float* __restrict__ dinv,
                                                   int* __restrict__ ebuf, int n) {
    __shared__ int cnt[256], lb[256], lf[256], sc[256];
    int tid = threadIdx.x, k = blockIdx.x;
    int seg0 = k * SEGW, seg1 = seg0 + bucket_fill[k];
    cnt[tid] = 0;
    lf[tid] = 0;
    __syncthreads();
    for (int j = seg0 + tid; j < seg1; j += 256)
        atomicAdd(&cnt[rbuf[j] >> 24], 1);
    __syncthreads();
    int cv = cnt[tid];
    sc[tid] = cv;
    __syncthreads();
    int val = cv;
    for (int off = 1; off < 256; off <<= 1) {
        int t = (tid >= off) ? sc[tid - off] : 0;
        __syncthreads();
        val += t;
        sc[tid] = val;
        __syncthreads();
    }
    lb[tid] = val - cv;   // exclusive
    __syncthreads();
    int node = k * 256 + tid;
    if (node < n) {
        float dv = rsqrtf((float)cv + 1.f);
        int4 m;
        m.x = seg0 + lb[tid];
        m.y = cv;
        m.z = __float_as_int(dv);
        m.w = 0;
        meta[node] = m;
        dinv[node] = dv;
    }
    for (int j = seg0 + tid; j < seg1; j += 256) {
        unsigned int r = rbuf[j];
        int dl = r >> 24;
        int p = seg0 + lb[dl] + atomicAdd(&lf[dl], 1);
        ebuf[p] = (int)(r & 0xFFFFFFu);
    }
}

// ---------------------------------------------------------------------------
// 5) Gather + finalize (quarter-wave, known-good): 16 lanes x 16B = 256B
//    full-row reads; per-edge dinv[src] applied via fma.
// ---------------------------------------------------------------------------
__global__ __launch_bounds__(256) void gather_kernel(const uint4* __restrict__ xb4,
                                                     const int4* __restrict__ meta,
                                                     const int* __restrict__ ebuf,
                                                     const float* __restrict__ dinv,
                                                     const float* __restrict__ bias,
                                                     const float* __restrict__ pa,
                                                     float* __restrict__ out, int n) {
    int tid = threadIdx.x;
    int sub = tid & 15;                               // sublane in quarter-wave
    int node = (blockIdx.x * 256 + tid) >> 4;         // one node per 16 lanes
    if (node >= n) return;

    int4 m = meta[node];
    int b = m.x, deg = m.y;
    float dn = __int_as_float(m.z);

    uint4 s0 = xb4[(size_t)node * 16 + sub];
    float a0 = dn * __uint_as_float(s0.x << 16);
    float a1 = dn * __uint_as_float(s0.x & 0xffff0000u);
    float a2 = dn * __uint_as_float(s0.y << 16);
    float a3 = dn * __uint_as_float(s0.y & 0xffff0000u);
    float a4 = dn * __uint_as_float(s0.z << 16);
    float a5 = dn * __uint_as_float(s0.z & 0xffff0000u);
    float a6 = dn * __uint_as_float(s0.w << 16);
    float a7 = dn * __uint_as_float(s0.w & 0xffff0000u);

    int k = 0;
    for (; k + 4 <= deg; k += 4) {
        int r0 = ebuf[b + k + 0];
        int r1 = ebuf[b + k + 1];
        int r2 = ebuf[b + k + 2];
        int r3 = ebuf[b + k + 3];
        float d0 = dinv[r0], d1 = dinv[r1], d2 = dinv[r2], d3 = dinv[r3];
        uint4 v0 = xb4[(size_t)r0 * 16 + sub];
        uint4 v1 = xb4[(size_t)r1 * 16 + sub];
        uint4 v2 = xb4[(size_t)r2 * 16 + sub];
        uint4 v3 = xb4[(size_t)r3 * 16 + sub];
        a0 += d0 * __uint_as_float(v0.x << 16) + d1 * __uint_as_float(v1.x << 16)
            + d2 * __uint_as_float(v2.x << 16) + d3 * __uint_as_float(v3.x << 16);
        a1 += d0 * __uint_as_float(v0.x & 0xffff0000u) + d1 * __uint_as_float(v1.x & 0xffff0000u)
            + d2 * __uint_as_float(v2.x & 0xffff0000u) + d3 * __uint_as_float(v3.x & 0xffff0000u);
        a2 += d0 * __uint_as_float(v0.y << 16) + d1 * __uint_as_float(v1.y << 16)
            + d2 * __uint_as_float(v2.y << 16) + d3 * __uint_as_float(v3.y << 16);
        a3 += d0 * __uint_as_float(v0.y & 0xffff0000u) + d1 * __uint_as_float(v1.y & 0xffff0000u)
            + d2 * __uint_as_float(v2.y & 0xffff0000u) + d3 * __uint_as_float(v3.y & 0xffff0000u);
        a4 += d0 * __uint_as_float(v0.z << 16) + d1 * __uint_as_float(v1.z << 16)
            + d2 * __uint_as_float(v2.z << 16) + d3 * __uint_as_float(v3.z << 16);
        a5 += d0 * __uint_as_float(v0.z & 0xffff0000u) + d1 * __uint_as_float(v1.z & 0xffff0000u)
            + d2 * __uint_as_float(v2.z & 0xffff0000u) + d3 * __uint_as_float(v3.z & 0xffff0000u);
        a6 += d0 * __uint_as_float(v0.w << 16) + d1 * __uint_as_float(v1.w << 16)
            + d2 * __uint_as_float(v2.w << 16) + d3 * __uint_as_float(v3.w << 16);
        a7 += d0 * __uint_as_float(v0.w & 0xffff0000u) + d1 * __uint_as_float(v1.w & 0xffff0000u)
            + d2 * __uint_as_float(v2.w & 0xffff0000u) + d3 * __uint_as_float(v3.w & 0xffff0000u);
    }
    for (; k < deg; ++k) {
        int r = ebuf[b + k];
        float d = dinv[r];
        uint4 v = xb4[(size_t)r * 16 + sub];
        a0 += d * __uint_as_float(v.x << 16);
        a1 += d * __uint_as_float(v.x & 0xffff0000u);
        a2 += d * __uint_as_float(v.y << 16);
        a3 += d * __uint_as_float(v.y & 0xffff0000u);
        a4 += d * __uint_as_float(v.z << 16);
        a5 += d * __uint_as_float(v.z & 0xffff0000u);
        a6 += d * __uint_as_float(v.w << 16);
        a7 += d * __uint_as_float(v.w & 0xffff0000u);
    }

    float alpha = pa[0];
    const float4* bb4 = (const float4*)bias;
    float4 b0 = bb4[sub * 2], b1 = bb4[sub * 2 + 1];
    float o0 = dn * a0 + b0.x;
    float o1 = dn * a1 + b0.y;
    float o2 = dn * a2 + b0.z;
    float o3 = dn * a3 + b0.w;
    float o4 = dn * a4 + b1.x;
    float o5 = dn * a5 + b1.y;
    float o6 = dn * a6 + b1.z;
    float o7 = dn * a7 + b1.w;
    o0 = o0 > 0.f ? o0 : alpha * o0;
    o1 = o1 > 0.f ? o1 : alpha * o1;
    o2 = o2 > 0.f ? o2 : alpha * o2;
    o3 = o3 > 0.f ? o3 : alpha * o3;
    o4 = o4 > 0.f ? o4 : alpha * o4;
    o5 = o5 > 0.f ? o5 : alpha * o5;
    o6 = o6 > 0.f ? o6 : alpha * o6;
    o7 = o7 > 0.f ? o7 : alpha * o7;
    float4* orow = (float4*)out + (size_t)node * 32 + sub * 2;
    orow[0] = make_float4(o0, o1, o2, o3);
    orow[1] = make_float4(o4, o5, o6, o7);
}

// ---------------------------------------------------------------------------
extern "C" void kernel_launch(void* const* d_in, const int* in_sizes, int n_in,
                              void* d_out, int out_size, void* d_ws, size_t ws_size,
                              hipStream_t stream) {
    const float* x    = (const float*)d_in[0];
    const int*   ei   = (const int*)d_in[1];   // int32, [2,E] row-major
    const float* W    = (const float*)d_in[2];
    const float* bias = (const float*)d_in[3];
    const float* pa   = (const float*)d_in[4];
    const float* u    = (const float*)d_in[5];

    int n = in_sizes[0] / NFEAT;     // 100000
    int e = in_sizes[1] / 2;         // 1600000
    const int* erow = ei;            // sources
    const int* ecol = ei + e;        // targets

    float* out = (float*)d_out;
    char* ws = (char*)d_ws;
    // workspace layout (bytes)
    float*        scal   = (float*)(ws);                    // 4 B
    int*          bfill  = (int*)  (ws + 0x0002000);        // 391 ints
    __bf16*       WT     = (__bf16*)(ws + 0x0010000);       // 64 KB
    float*        dinv   = (float*)(ws + 0x0100000);        // 400 KB
    int4*         meta   = (int4*) (ws + 0x0200000);        // 1.6 MB
    unsigned int* rbuf   = (unsigned int*)(ws + 0x0400000); // 7.2 MB (391*4608*4)
    int*          ebuf   = (int*)  (ws + 0x0B00000);        // 7.2 MB
    __bf16*       xwb    = (__bf16*)(ws + 0x1200000);       // 25.6 MB

    int ngemm = (n + 63) / 64;       // 1563

    sigma_kernel<<<1, 256, 0, stream>>>(W, u, scal, bfill);
    wt_kernel<<<(NFEAT * NHID) / 256, 256, 0, stream>>>(W, scal, WT);

    fused_kernel<<<ngemm + NBLK, 256, 0, stream>>>(x, WT, xwb, erow, ecol,
                                                   bfill, rbuf, n, e, ngemm);

    fine_kernel<<<NBK, 256, 0, stream>>>(rbuf, bfill, meta, dinv, ebuf, n);

    long long gunits = (long long)n * 16;
    gather_kernel<<<(int)((gunits + 255) / 256), 256, 0, stream>>>(
        (const uint4*)xwb, meta, ebuf, dinv, bias, pa, out, n);
}

// Round 17
// 144.337 us; speedup vs baseline: 1.9766x; 1.0083x over previous
//
#include <hip/hip_runtime.h>

#define NFEAT 256
#define NHID  128

#define NBK   391     // node buckets of 256 nodes (ceil(100000/256))
#define EPB   4096    // edges per block in the coarse pass
#define NBLK  391     // edge blocks (ceil(1600000/4096))
#define SEGW  4608    // fixed bucket segment stride (mean 4092 + 8 sigma)

typedef __bf16 bf16x8 __attribute__((ext_vector_type(8)));
typedef __bf16 bf16x4 __attribute__((ext_vector_type(4)));
typedef float  f32x4  __attribute__((ext_vector_type(4)));

#define PIN() __builtin_amdgcn_sched_barrier(0)

// ---------------------------------------------------------------------------
// 1) Spectral norm (one power iteration) -> scal[0] = 1/sigma.
//    Also zeroes the global bucket_fill counters (free ride, 1 block).
// ---------------------------------------------------------------------------
__global__ __launch_bounds__(256) void sigma_kernel(const float* __restrict__ W,
                                                    const float* __restrict__ u,
                                                    float* __restrict__ scal,
                                                    int* __restrict__ bucket_fill) {
    __shared__ float v[NHID];
    __shared__ float red[256];
    int tid = threadIdx.x;

    if (tid < NBK) bucket_fill[tid] = 0;
    if (tid + 256 < NBK) bucket_fill[tid + 256] = 0;

    float t = 0.f;
    if (tid < NHID) {
        for (int i = 0; i < NFEAT; ++i) t += W[i * NHID + tid] * u[i];
    }
    red[tid] = (tid < NHID) ? t * t : 0.f;
    __syncthreads();
    for (int s = 128; s > 0; s >>= 1) {
        if (tid < s) red[tid] += red[tid + s];
        __syncthreads();
    }
    float nv = sqrtf(red[0]);
    float inv_nv = 1.f / (nv + 1e-12f);
    __syncthreads();
    if (tid < NHID) v[tid] = t * inv_nv;
    __syncthreads();

    float wv = 0.f;
    for (int j = 0; j < NHID; ++j) wv += W[tid * NHID + j] * v[j];
    red[tid] = wv * wv;
    __syncthreads();
    for (int s = 128; s > 0; s >>= 1) {
        if (tid < s) red[tid] += red[tid + s];
        __syncthreads();
    }
    if (tid == 0) {
        float n2  = red[0];
        float nwv = sqrtf(n2);
        float sigma = n2 / (nwv + 1e-12f);
        scal[0] = 1.f / sigma;
    }
}

// ---------------------------------------------------------------------------
// 2) W^T in bf16, scaled by 1/sigma
// ---------------------------------------------------------------------------
__global__ __launch_bounds__(256) void wt_kernel(const float* __restrict__ W,
                                                 const float* __restrict__ scal,
                                                 __bf16* __restrict__ WT) {
    int idx = blockIdx.x * 256 + threadIdx.x;
    int c = idx >> 8;
    int r = idx & 255;
    WT[c * NFEAT + r] = (__bf16)(W[r * NHID + c] * scal[0]);
}

// ---------------------------------------------------------------------------
// 3) FUSED kernel:
//    blocks [0, ngemm)  = MFMA GEMM, 128 rows/block, WAVE-PRIVATE tiles:
//      wave w owns rows [w*32, w*32+32) for staging AND compute -> ZERO
//      barriers; per-wave 2-buffer pipeline with counted vmcnt(4).
//      K in 8 chunks of 32. Ledger/wave: [S(c):4][B(c):8][S(c+1):4]
//      -> vmcnt(4) retires S(c)+B(c), S(c+1) stays in flight.
//    blocks [ngemm, ngemm+NBLK) = coarse edge bucketing. Union LDS 32KB.
// ---------------------------------------------------------------------------
__global__ __launch_bounds__(256) void fused_kernel(const float* __restrict__ x,
                                                    const __bf16* __restrict__ WT,
                                                    __bf16* __restrict__ xwb,
                                                    const int* __restrict__ erow,
                                                    const int* __restrict__ ecol,
                                                    int* __restrict__ bucket_fill,
                                                    unsigned int* __restrict__ rbuf,
                                                    int nn, int E, int ngemm) {
    __shared__ __attribute__((aligned(16))) char sbuf[32768];   // 32KB union

    int tid  = threadIdx.x;

    if ((int)blockIdx.x < ngemm) {
        // ============ GEMM path (barrier-free, wave-private rows) ===========
        float (*xs)[128][32] = (float (*)[128][32])sbuf;   // 2 x 16KB

        int lane = tid & 63;
        int w    = tid >> 6;                 // wave 0..3
        int rfrag = lane & 15;
        int kg    = lane >> 4;               // 0..3
        int row0 = blockIdx.x * 128;

        int p8   = lane & 7;                 // staging: 16B slot within 128B row
        int rsub = lane >> 3;                // staging: row within 8-row group

        int crow0 = w * 32 + rfrag;          // chain rows crow0, crow0+16
        int r0 = row0 + crow0;
        int r1 = r0 + 16;
        const __bf16* wb = WT + (size_t)rfrag * NFEAT + kg * 8;
        int cr7 = crow0 & 7;                 // == (crow0+16)&7

        f32x4 acc0[8] = {};
        f32x4 acc1[8] = {};

        // stage chunk c (K=32 cols) of this wave's 32 rows -> 4 gload_lds
        auto STAGE = [&](int buf, int c) {
#pragma unroll
            for (int j = 0; j < 4; ++j) {
                int rloc = w * 32 + j * 8 + rsub;
                int grow = row0 + rloc;
                if (grow >= nn) grow = nn - 1;
                const float* src = x + (size_t)grow * NFEAT + c * 32 + ((p8 ^ (grow & 7)) << 2);
                __builtin_amdgcn_global_load_lds(
                    (const __attribute__((address_space(1))) void*)src,
                    (__attribute__((address_space(3))) void*)&xs[buf][w * 32 + j * 8][0],
                    16, 0, 0);
            }
        };

        bf16x8 Bf[8];                        // all 128 cols for this chunk
        auto BLOAD = [&](int c) {
#pragma unroll
            for (int nt = 0; nt < 8; ++nt)
                Bf[nt] = *(const bf16x8*)(wb + (size_t)nt * 16 * NFEAT + c * 32);
        };

        auto MFMA_CHUNK = [&](int buf) {
            int s0 = ((kg * 2) ^ cr7) * 4;
            int s1 = ((kg * 2 + 1) ^ cr7) * 4;
            float4 a0lo = *(const float4*)&xs[buf][crow0][s0];
            float4 a0hi = *(const float4*)&xs[buf][crow0][s1];
            float4 a1lo = *(const float4*)&xs[buf][crow0 + 16][s0];
            float4 a1hi = *(const float4*)&xs[buf][crow0 + 16][s1];
            bf16x8 af0, af1;
            af0[0] = (__bf16)a0lo.x; af0[1] = (__bf16)a0lo.y;
            af0[2] = (__bf16)a0lo.z; af0[3] = (__bf16)a0lo.w;
            af0[4] = (__bf16)a0hi.x; af0[5] = (__bf16)a0hi.y;
            af0[6] = (__bf16)a0hi.z; af0[7] = (__bf16)a0hi.w;
            af1[0] = (__bf16)a1lo.x; af1[1] = (__bf16)a1lo.y;
            af1[2] = (__bf16)a1lo.z; af1[3] = (__bf16)a1lo.w;
            af1[4] = (__bf16)a1hi.x; af1[5] = (__bf16)a1hi.y;
            af1[6] = (__bf16)a1hi.z; af1[7] = (__bf16)a1hi.w;
#pragma unroll
            for (int nt = 0; nt < 8; ++nt) {
                acc0[nt] = __builtin_amdgcn_mfma_f32_16x16x32_bf16(Bf[nt], af0, acc0[nt], 0, 0, 0);
                acc1[nt] = __builtin_amdgcn_mfma_f32_16x16x32_bf16(Bf[nt], af1, acc1[nt], 0, 0, 0);
            }
        };

        // ---- per-wave pipeline, no barriers
        STAGE(0, 0);  PIN();                       // S0
#pragma unroll
        for (int c = 0; c < 8; ++c) {
            BLOAD(c);  PIN();                      // B(c)
            if (c < 7) { STAGE((c + 1) & 1, c + 1);  PIN(); }   // S(c+1)
            if (c < 7) asm volatile("s_waitcnt vmcnt(4)" ::: "memory");  // S(c)+B(c) done
            else       asm volatile("s_waitcnt vmcnt(0)" ::: "memory");
            MFMA_CHUNK(c & 1);
        }

        // ---- epilogue: lane owns rows r0/r1, cols nt*16 + kg*4 + reg
        if (r0 < nn) {
            __bf16* orow = xwb + (size_t)r0 * NHID + kg * 4;
#pragma unroll
            for (int nt = 0; nt < 8; ++nt) {
                bf16x4 v;
                v[0] = (__bf16)acc0[nt][0];
                v[1] = (__bf16)acc0[nt][1];
                v[2] = (__bf16)acc0[nt][2];
                v[3] = (__bf16)acc0[nt][3];
                *(bf16x4*)&orow[nt * 16] = v;
            }
        }
        if (r1 < nn) {
            __bf16* orow = xwb + (size_t)r1 * NHID + kg * 4;
#pragma unroll
            for (int nt = 0; nt < 8; ++nt) {
                bf16x4 v;
                v[0] = (__bf16)acc1[nt][0];
                v[1] = (__bf16)acc1[nt][1];
                v[2] = (__bf16)acc1[nt][2];
                v[3] = (__bf16)acc1[nt][3];
                *(bf16x4*)&orow[nt * 16] = v;
            }
        }
        return;
    }

    // =================== COARSE path (fixed-stride segments) ===============
    unsigned int*   rec   = (unsigned int*)sbuf;               // 16384 B
    unsigned short* bkk   = (unsigned short*)(sbuf + 16384);   //  8192 B
    int*            hist  = (int*)(sbuf + 24576);              //  1564 B
    int*            lbase = (int*)(sbuf + 24576 + 1564);
    int*            lfill = (int*)(sbuf + 24576 + 3128);
    int*            gb    = (int*)(sbuf + 24576 + 4692);       // ends 30832

    int b = blockIdx.x - ngemm;
    for (int k = tid; k < NBK; k += 256) { hist[k] = 0; lfill[k] = 0; }
    __syncthreads();

    int e0 = b * EPB;
    unsigned int rv[16];
    int kv[16];
#pragma unroll
    for (int j = 0; j < 16; ++j) {
        int idx = e0 + j * 256 + tid;
        if (idx < E) {
            int c = ecol[idx];
            int s = erow[idx];
            int k = c >> 8;
            kv[j] = k;
            rv[j] = ((unsigned int)(c & 255) << 24) | (unsigned int)s;
            atomicAdd(&hist[k], 1);
        } else kv[j] = -1;
    }
    __syncthreads();

    // wave-0 shuffle scan of hist[0..390] -> lbase (exclusive)
    if (tid < 64) {
        int carry = 0;
        for (int c0 = 0; c0 < NBK; c0 += 64) {
            int i = c0 + tid;
            int vv = (i < NBK) ? hist[i] : 0;
            int orig = vv;
#pragma unroll
            for (int d = 1; d < 64; d <<= 1) {
                int t = __shfl_up(vv, (unsigned)d, 64);
                if (tid >= d) vv += t;
            }
            if (i < NBK) lbase[i] = carry + vv - orig;
            carry += __shfl(vv, 63, 64);
        }
    }
    __syncthreads();

    // reserve global span per bucket
    if (tid < NBK) gb[tid] = tid * SEGW + atomicAdd(&bucket_fill[tid], hist[tid]);
    if (tid + 256 < NBK) gb[tid + 256] = (tid + 256) * SEGW
                                       + atomicAdd(&bucket_fill[tid + 256], hist[tid + 256]);
    __syncthreads();

#pragma unroll
    for (int j = 0; j < 16; ++j) {
        if (kv[j] >= 0) {
            int p = lbase[kv[j]] + atomicAdd(&lfill[kv[j]], 1);
            rec[p] = rv[j];
            bkk[p] = (unsigned short)kv[j];
        }
    }
    __syncthreads();

    int nval = E - e0;
    if (nval > EPB) nval = EPB;
    for (int p = tid; p < nval; p += 256) {
        int k = bkk[p];
        rbuf[gb[k] + (p - lbase[k])] = rec[p];
    }
}

// ---------------------------------------------------------------------------
// 4) F: fine pass — one block per bucket. Writes per-node meta (base,cnt,dinv)
//    and the dinv array (for per-edge loads), then places sources into ebuf.
// ---------------------------------------------------------------------------
__global__ __launch_bounds__(256) void fine_kernel(const unsigned int* __restrict__ rbuf,
                                                   const int* __restrict__ bucket_fill,
                                                   int4* __restrict__ meta,
                                                   float* __restrict__ dinv,
                                                   int* __restrict__ ebuf, int n) {
    __shared__ int cnt[256], lb[256], lf[256], sc[256];
    int tid = threadIdx.x, k = blockIdx.x;
    int seg0 = k * SEGW, seg1 = seg0 + bucket_fill[k];
    cnt[tid] = 0;
    lf[tid] = 0;
    __syncthreads();
    for (int j = seg0 + tid; j < seg1; j += 256)
        atomicAdd(&cnt[rbuf[j] >> 24], 1);
    __syncthreads();
    int cv = cnt[tid];
    sc[tid] = cv;
    __syncthreads();
    int val = cv;
    for (int off = 1; off < 256; off <<= 1) {
        int t = (tid >= off) ? sc[tid - off] : 0;
        __syncthreads();
        val += t;
        sc[tid] = val;
        __syncthreads();
    }
    lb[tid] = val - cv;   // exclusive
    __syncthreads();
    int node = k * 256 + tid;
    if (node < n) {
        float dv = rsqrtf((float)cv + 1.f);
        int4 m;
        m.x = seg0 + lb[tid];
        m.y = cv;
        m.z = __float_as_int(dv);
        m.w = 0;
        meta[node] = m;
        dinv[node] = dv;
    }
    for (int j = seg0 + tid; j < seg1; j += 256) {
        unsigned int r = rbuf[j];
        int dl = r >> 24;
        int p = seg0 + lb[dl] + atomicAdd(&lf[dl], 1);
        ebuf[p] = (int)(r & 0xFFFFFFu);
    }
}

// ---------------------------------------------------------------------------
// 5) Gather + finalize (quarter-wave, known-good): 16 lanes x 16B = 256B
//    full-row reads; per-edge dinv[src] applied via fma.
// ---------------------------------------------------------------------------
__global__ __launch_bounds__(256) void gather_kernel(const uint4* __restrict__ xb4,
                                                     const int4* __restrict__ meta,
                                                     const int* __restrict__ ebuf,
                                                     const float* __restrict__ dinv,
                                                     const float* __restrict__ bias,
                                                     const float* __restrict__ pa,
                                                     float* __restrict__ out, int n) {
    int tid = threadIdx.x;
    int sub = tid & 15;                               // sublane in quarter-wave
    int node = (blockIdx.x * 256 + tid) >> 4;         // one node per 16 lanes
    if (node >= n) return;

    int4 m = meta[node];
    int b = m.x, deg = m.y;
    float dn = __int_as_float(m.z);

    uint4 s0 = xb4[(size_t)node * 16 + sub];
    float a0 = dn * __uint_as_float(s0.x << 16);
    float a1 = dn * __uint_as_float(s0.x & 0xffff0000u);
    float a2 = dn * __uint_as_float(s0.y << 16);
    float a3 = dn * __uint_as_float(s0.y & 0xffff0000u);
    float a4 = dn * __uint_as_float(s0.z << 16);
    float a5 = dn * __uint_as_float(s0.z & 0xffff0000u);
    float a6 = dn * __uint_as_float(s0.w << 16);
    float a7 = dn * __uint_as_float(s0.w & 0xffff0000u);

    int k = 0;
    for (; k + 4 <= deg; k += 4) {
        int r0 = ebuf[b + k + 0];
        int r1 = ebuf[b + k + 1];
        int r2 = ebuf[b + k + 2];
        int r3 = ebuf[b + k + 3];
        float d0 = dinv[r0], d1 = dinv[r1], d2 = dinv[r2], d3 = dinv[r3];
        uint4 v0 = xb4[(size_t)r0 * 16 + sub];
        uint4 v1 = xb4[(size_t)r1 * 16 + sub];
        uint4 v2 = xb4[(size_t)r2 * 16 + sub];
        uint4 v3 = xb4[(size_t)r3 * 16 + sub];
        a0 += d0 * __uint_as_float(v0.x << 16) + d1 * __uint_as_float(v1.x << 16)
            + d2 * __uint_as_float(v2.x << 16) + d3 * __uint_as_float(v3.x << 16);
        a1 += d0 * __uint_as_float(v0.x & 0xffff0000u) + d1 * __uint_as_float(v1.x & 0xffff0000u)
            + d2 * __uint_as_float(v2.x & 0xffff0000u) + d3 * __uint_as_float(v3.x & 0xffff0000u);
        a2 += d0 * __uint_as_float(v0.y << 16) + d1 * __uint_as_float(v1.y << 16)
            + d2 * __uint_as_float(v2.y << 16) + d3 * __uint_as_float(v3.y << 16);
        a3 += d0 * __uint_as_float(v0.y & 0xffff0000u) + d1 * __uint_as_float(v1.y & 0xffff0000u)
            + d2 * __uint_as_float(v2.y & 0xffff0000u) + d3 * __uint_as_float(v3.y & 0xffff0000u);
        a4 += d0 * __uint_as_float(v0.z << 16) + d1 * __uint_as_float(v1.z << 16)
            + d2 * __uint_as_float(v2.z << 16) + d3 * __uint_as_float(v3.z << 16);
        a5 += d0 * __uint_as_float(v0.z & 0xffff0000u) + d1 * __uint_as_float(v1.z & 0xffff0000u)
            + d2 * __uint_as_float(v2.z & 0xffff0000u) + d3 * __uint_as_float(v3.z & 0xffff0000u);
        a6 += d0 * __uint_as_float(v0.w << 16) + d1 * __uint_as_float(v1.w << 16)
            + d2 * __uint_as_float(v2.w << 16) + d3 * __uint_as_float(v3.w << 16);
        a7 += d0 * __uint_as_float(v0.w & 0xffff0000u) + d1 * __uint_as_float(v1.w & 0xffff0000u)
            + d2 * __uint_as_float(v2.w & 0xffff0000u) + d3 * __uint_as_float(v3.w & 0xffff0000u);
    }
    for (; k < deg; ++k) {
        int r = ebuf[b + k];
        float d = dinv[r];
        uint4 v = xb4[(size_t)r * 16 + sub];
        a0 += d * __uint_as_float(v.x << 16);
        a1 += d * __uint_as_float(v.x & 0xffff0000u);
        a2 += d * __uint_as_float(v.y << 16);
        a3 += d * __uint_as_float(v.y & 0xffff0000u);
        a4 += d * __uint_as_float(v.z << 16);
        a5 += d * __uint_as_float(v.z & 0xffff0000u);
        a6 += d * __uint_as_float(v.w << 16);
        a7 += d * __uint_as_float(v.w & 0xffff0000u);
    }

    float alpha = pa[0];
    const float4* bb4 = (const float4*)bias;
    float4 b0 = bb4[sub * 2], b1 = bb4[sub * 2 + 1];
    float o0 = dn * a0 + b0.x;
    float o1 = dn * a1 + b0.y;
    float o2 = dn * a2 + b0.z;
    float o3 = dn * a3 + b0.w;
    float o4 = dn * a4 + b1.x;
    float o5 = dn * a5 + b1.y;
    float o6 = dn * a6 + b1.z;
    float o7 = dn * a7 + b1.w;
    o0 = o0 > 0.f ? o0 : alpha * o0;
    o1 = o1 > 0.f ? o1 : alpha * o1;
    o2 = o2 > 0.f ? o2 : alpha * o2;
    o3 = o3 > 0.f ? o3 : alpha * o3;
    o4 = o4 > 0.f ? o4 : alpha * o4;
    o5 = o5 > 0.f ? o5 : alpha * o5;
    o6 = o6 > 0.f ? o6 : alpha * o6;
    o7 = o7 > 0.f ? o7 : alpha * o7;
    float4* orow = (float4*)out + (size_t)node * 32 + sub * 2;
    orow[0] = make_float4(o0, o1, o2, o3);
    orow[1] = make_float4(o4, o5, o6, o7);
}

// ---------------------------------------------------------------------------
extern "C" void kernel_launch(void* const* d_in, const int* in_sizes, int n_in,
                              void* d_out, int out_size, void* d_ws, size_t ws_size,
                              hipStream_t stream) {
    const float* x    = (const float*)d_in[0];
    const int*   ei   = (const int*)d_in[1];   // int32, [2,E] row-major
    const float* W    = (const float*)d_in[2];
    const float* bias = (const float*)d_in[3];
    const float* pa   = (const float*)d_in[4];
    const float* u    = (const float*)d_in[5];

    int n = in_sizes[0] / NFEAT;     // 100000
    int e = in_sizes[1] / 2;         // 1600000
    const int* erow = ei;            // sources
    const int* ecol = ei + e;        // targets

    float* out = (float*)d_out;
    char* ws = (char*)d_ws;
    // workspace layout (bytes)
    float*        scal   = (float*)(ws);                    // 4 B
    int*          bfill  = (int*)  (ws + 0x0002000);        // 391 ints
    __bf16*       WT     = (__bf16*)(ws + 0x0010000);       // 64 KB
    float*        dinv   = (float*)(ws + 0x0100000);        // 400 KB
    int4*         meta   = (int4*) (ws + 0x0200000);        // 1.6 MB
    unsigned int* rbuf   = (unsigned int*)(ws + 0x0400000); // 7.2 MB (391*4608*4)
    int*          ebuf   = (int*)  (ws + 0x0B00000);        // 7.2 MB
    __bf16*       xwb    = (__bf16*)(ws + 0x1200000);       // 25.6 MB

    int ngemm = (n + 127) / 128;     // 782

    sigma_kernel<<<1, 256, 0, stream>>>(W, u, scal, bfill);
    wt_kernel<<<(NFEAT * NHID) / 256, 256, 0, stream>>>(W, scal, WT);

    fused_kernel<<<ngemm + NBLK, 256, 0, stream>>>(x, WT, xwb, erow, ecol,
                                                   bfill, rbuf, n, e, ngemm);

    fine_kernel<<<NBK, 256, 0, stream>>>(rbuf, bfill, meta, dinv, ebuf, n);

    long long gunits = (long long)n * 16;
    gather_kernel<<<(int)((gunits + 255) / 256), 256, 0, stream>>>(
        (const uint4*)xwb, meta, ebuf, dinv, bias, pa, out, n);
}